// Round 1
// baseline (651.151 us; speedup 1.0000x reference)
//
#include <hip/hip_runtime.h>
#include <math.h>

// CTC forward loss, warp-ctc semantics (softmax applied internally).
// T=1024, B=64, V=128, L=256 -> S=513. Output: scalar sum of per-example NLL.

#define NEGF (-1e30f)

constexpr int T = 1024;
constexpr int B = 64;
constexpr int V = 128;
constexpr int L = 256;
constexpr int S = 2 * L + 1;   // 513
constexpr int BLK = 512;       // 8 waves
constexpr int NW = BLK / 64;   // 8 waves per block

__global__ __launch_bounds__(BLK) void ctc_alpha_kernel(
    const float* __restrict__ acts,        // (T, B, V)
    const int* __restrict__ labels,        // (B, L) flat
    const int* __restrict__ act_lens,      // (B,)
    const int* __restrict__ label_lens,    // (B,)
    float* __restrict__ out) {             // scalar accumulator (pre-zeroed)
  const int b = blockIdx.x;
  const int tid = threadIdx.x;
  const int wave = tid >> 6;
  const int lane = tid & 63;

  __shared__ float alpha[2][S];
  __shared__ float row[2][V];       // emission rows (log-softmax'd), double buffered
  __shared__ float s_denom[T];      // per-t log-softmax denominator (max + lse)
  __shared__ int ext_s[S];
  __shared__ unsigned char allow_s[S];

  const int* lab = labels + b * L;

  // ---- extended label sequence + skip-allow mask ----
  for (int s = tid; s < S; s += BLK) {
    int e = (s & 1) ? lab[s >> 1] : 0;
    ext_s[s] = e;
    allow_s[s] = (unsigned char)((s & 1) && (s >= 3) && (e != 0) &&
                                 (e != lab[(s - 2) >> 1]));
  }

  // ---- per-t log-softmax denominators: wave w handles t = w, w+8, ... ----
  for (int t = wave; t < T; t += NW) {
    const float* p = acts + ((size_t)t * B + b) * V;
    float a = p[lane];
    float c = p[lane + 64];
    float mx = fmaxf(a, c);
    #pragma unroll
    for (int off = 32; off; off >>= 1) mx = fmaxf(mx, __shfl_down(mx, off));
    mx = __shfl(mx, 0);
    float sm = __expf(a - mx) + __expf(c - mx);
    #pragma unroll
    for (int off = 32; off; off >>= 1) sm += __shfl_down(sm, off);
    if (lane == 0) s_denom[t] = mx + __logf(sm);
  }
  __syncthreads();

  // ---- stage rows 0 and 1 ----
  if (tid < V) {
    row[0][tid] = acts[((size_t)0 * B + b) * V + tid] - s_denom[0];
    row[1][tid] = acts[((size_t)1 * B + b) * V + tid] - s_denom[1];
  }
  __syncthreads();

  // ---- alpha init (t = 0) ----
  for (int s = tid; s < S; s += BLK) {
    alpha[0][s] = (s <= 1) ? row[0][ext_s[s]] : NEGF;
  }
  __syncthreads();

  const int AL = act_lens[b];

  // prefetch row t=2 into registers
  float pre = 0.f;
  if (tid < V) pre = acts[((size_t)2 * B + b) * V + tid];

  int cur = 0;
  for (int t = 1; t < T; ++t) {
    const float* __restrict__ rw = row[t & 1];
    const float* __restrict__ ac = alpha[cur];
    float* __restrict__ an = alpha[cur ^ 1];
    const bool live = (t < AL);
    for (int s = tid; s < S; s += BLK) {
      float a  = ac[s];
      float p1 = (s >= 1) ? ac[s - 1] : NEGF;
      float p2 = allow_s[s] ? ac[s - 2] : NEGF;
      float m  = fmaxf(a, fmaxf(p1, p2));
      float l  = __expf(a - m) + __expf(p1 - m) + __expf(p2 - m);
      float nv = m + __logf(l) + rw[ext_s[s]];
      an[s] = live ? nv : a;
    }
    __syncthreads();   // all reads of row[t&1] / alpha[cur] done; alpha[cur^1] visible
    if (t + 1 < T) {
      if (tid < V) {
        row[(t + 1) & 1][tid] = pre - s_denom[t + 1];
        if (t + 2 < T) pre = acts[((size_t)(t + 2) * B + b) * V + tid];
      }
      __syncthreads(); // staged row visible before next iteration's compute
    }
    cur ^= 1;
  }

  // ---- epilogue: cost_b = -logaddexp(alpha[end], alpha[end-1]) ----
  if (tid == 0) {
    int end = 2 * label_lens[b];
    float a0 = alpha[cur][end];
    float a1 = alpha[cur][end - 1];
    float m = fmaxf(a0, a1);
    float cost = -(m + __logf(__expf(a0 - m) + __expf(a1 - m)));
    atomicAdd(out, cost);
  }
}

extern "C" void kernel_launch(void* const* d_in, const int* in_sizes, int n_in,
                              void* d_out, int out_size, void* d_ws, size_t ws_size,
                              hipStream_t stream) {
  const float* acts       = (const float*)d_in[0];
  const int*   labels     = (const int*)d_in[1];
  const int*   act_lens   = (const int*)d_in[2];
  const int*   label_lens = (const int*)d_in[3];
  float* out = (float*)d_out;

  hipMemsetAsync(out, 0, sizeof(float) * out_size, stream);
  ctc_alpha_kernel<<<B, BLK, 0, stream>>>(acts, labels, act_lens, label_lens, out);
}

// Round 2
// 410.627 us; speedup vs baseline: 1.5857x; 1.5857x over previous
//
#include <hip/hip_runtime.h>
#include <math.h>

// CTC forward loss (warp-ctc semantics: softmax applied internally).
// T=1024, B=64, V=128, L=256 -> S=513. Output: scalar sum of per-example NLL.
//
// Design (round 2): one block per batch, one DP cell per thread (9 waves).
// alpha in registers; s-1/s-2 via __shfl_up; wave-boundary cells via tiny
// double-buffered LDS "edges" array. ONE raw barrier per step
// (s_waitcnt lgkmcnt(0); s_barrier) so global emission prefetch loads stay
// in flight across the barrier (no vmcnt(0) drain). All math in base-2
// (v_exp_f32 / v_log_f32 are native exp2/log2).

#define NEGF (-1e30f)
#define L2E  1.4426950408889634f
#define LN2  0.6931471805599453f

constexpr int T = 1024;
constexpr int B = 64;
constexpr int V = 128;
constexpr int L = 256;
constexpr int S = 2 * L + 1;     // 513
constexpr int NW = 9;            // waves per block
constexpr int BLK = NW * 64;     // 576 threads: thread s owns cell s (s < 513)
constexpr int BV = B * V;        // acts row stride in floats

#if __has_builtin(__builtin_amdgcn_exp2f)
#define FEXP2(x) __builtin_amdgcn_exp2f(x)
#else
#define FEXP2(x) exp2f(x)
#endif
#if __has_builtin(__builtin_amdgcn_log2f)
#define FLOG2(x) __builtin_amdgcn_log2f(x)
#else
#define FLOG2(x) log2f(x)
#endif

// LDS-only barrier: drain lgkmcnt (our ds ops) but leave global loads
// (vmcnt) in flight. Cross-thread comms in the main loop are LDS-only.
#define BAR() asm volatile("s_waitcnt lgkmcnt(0)\n\ts_barrier" ::: "memory")

__global__ __launch_bounds__(BLK) void ctc_kernel(
    const float* __restrict__ acts,        // (T, B, V)
    const int* __restrict__ labels,        // (B, L)
    const int* __restrict__ act_lens,      // (B,)
    const int* __restrict__ label_lens,    // (B,)
    float* __restrict__ out) {             // scalar (pre-zeroed)
  const int b    = blockIdx.x;
  const int tid  = threadIdx.x;
  const int wv   = tid >> 6;
  const int lane = tid & 63;
  const int s    = tid;                    // owned cell (valid if s < S)

  __shared__ float  denom2[T];             // base-2 log-softmax denominators
  __shared__ float2 edges[2][NW + 1];      // [buf][wave]{lane62,lane63}; row NW = NEG pad
  __shared__ float  fin[2];

  if (tid < 2) {
    edges[tid][NW] = make_float2(NEGF, NEGF);
  }

  // ---- per-thread label / allow-mask registers ----
  const int* lab = labels + b * L;
  int e = 0;
  float amask = NEGF;                      // additive mask on p2 (0 = allowed)
  if (s < S && (s & 1)) {
    e = lab[s >> 1];
    if (s >= 3) {
      int eprev = lab[(s >> 1) - 1];
      if (e != 0 && e != eprev) amask = 0.f;
    }
  }

  // ---- denominators: one row per thread (2 strided passes cover T=1024) ----
  for (int r = tid; r < T; r += BLK) {
    const float4* p4 = (const float4*)(acts + ((size_t)r * B + b) * V);
    float mx = NEGF;
    #pragma unroll
    for (int i = 0; i < V / 4; ++i) {
      float4 v = p4[i];
      mx = fmaxf(mx, fmaxf(fmaxf(v.x, v.y), fmaxf(v.z, v.w)));
    }
    float mx2 = mx * L2E;
    float sm = 0.f;
    #pragma unroll
    for (int i = 0; i < V / 4; ++i) {
      float4 v = p4[i];
      sm += FEXP2(fmaf(v.x, L2E, -mx2)) + FEXP2(fmaf(v.y, L2E, -mx2)) +
            FEXP2(fmaf(v.z, L2E, -mx2)) + FEXP2(fmaf(v.w, L2E, -mx2));
    }
    denom2[r] = mx2 + FLOG2(sm);
  }
  __syncthreads();

  // ---- alpha init (t=0), base-2 domain ----
  const float* gp = acts + (size_t)b * V + e;      // own column, row t=0
  float a_old = NEGF;
  {
    float v0 = fmaf(gp[0], L2E, -denom2[0]);
    if (s <= 1) a_old = v0;                         // s<2 implies s<S
  }
  if (lane >= 62) {
    ((float*)&edges[0][wv])[lane - 62] = a_old;     // initial (t=0) edges
  }
  const int AL = act_lens[b];

  // emission prefetch pipeline (depth 2), raw act values for own column
  const float* gq = gp + BV;                        // row t=1
  float r1 = *gq; gq += BV;                         // for t=1
  float r2 = *gq; gq += BV;                         // for t=2
  float dn1 = denom2[1];

  __syncthreads();                                  // edges[0] + denom2 visible

  const int erow = (wv == 0) ? NW : (wv - 1);       // NEG pad row for wave 0

  for (int t = 1; t < T; ++t) {
    const int pb = (t - 1) & 1;
    // neighbor old alphas: in-wave via shuffle, cross-wave via edge LDS
    float p1 = __shfl_up(a_old, 1);
    float p2 = __shfl_up(a_old, 2);
    float2 ee = edges[pb][erow];
    if (lane == 0) { p1 = ee.y; p2 = ee.x; }
    else if (lane == 1) { p2 = ee.y; }
    // emission for this step (loaded 2 iterations ago)
    float em = fmaf(r1, L2E, -dn1);
    r1 = r2;
    if (t + 2 < T) { r2 = *gq; gq += BV; }
    if (t + 1 < T) dn1 = denom2[t + 1];
    // 3-way log2-sum-exp2
    float p2e = p2 + amask;
    float m   = fmaxf(a_old, fmaxf(p1, p2e));
    float sum = FEXP2(a_old - m) + FEXP2(p1 - m) + FEXP2(p2e - m);
    float nv  = m + FLOG2(sum) + em;
    float an  = (t < AL) ? nv : a_old;
    if (lane >= 62) {
      ((float*)&edges[t & 1][wv])[lane - 62] = an;
    }
    a_old = an;
    BAR();
  }

  // ---- epilogue: -logaddexp(alpha[end], alpha[end-1]) * ln2 ----
  const int end = 2 * label_lens[b];
  if (s == end) fin[0] = a_old;
  if (s == end - 1) fin[1] = a_old;
  __syncthreads();
  if (tid == 0) {
    float a0 = fin[0];
    float a1 = (end >= 1) ? fin[1] : NEGF;
    float m = fmaxf(a0, a1);
    float c2 = m + FLOG2(FEXP2(a0 - m) + FEXP2(a1 - m));
    atomicAdd(out, -c2 * LN2);
  }
}

extern "C" void kernel_launch(void* const* d_in, const int* in_sizes, int n_in,
                              void* d_out, int out_size, void* d_ws, size_t ws_size,
                              hipStream_t stream) {
  const float* acts       = (const float*)d_in[0];
  const int*   labels     = (const int*)d_in[1];
  const int*   act_lens   = (const int*)d_in[2];
  const int*   label_lens = (const int*)d_in[3];
  float* out = (float*)d_out;

  hipMemsetAsync(out, 0, sizeof(float) * out_size, stream);
  ctc_kernel<<<B, BLK, 0, stream>>>(acts, labels, act_lens, label_lens, out);
}

// Round 3
// 213.705 us; speedup vs baseline: 3.0470x; 1.9215x over previous
//
#include <hip/hip_runtime.h>
#include <hip/hip_fp16.h>
#include <math.h>

// CTC forward loss (warp-ctc semantics). T=1024, B=64, V=128, L=256, S=513.
//
// Round 3: linear-probability domain + single-wave-per-batch DP.
//  - Prologue kernel (chip-wide): P[b][t] = {softmax probs at the 256 label
//    positions, blank prob} in fp16 -> d_ws (34 MB). All transcendentals
//    happen here, throughput-bound.
//  - DP kernel: 64 blocks x 1 wave. Lane l owns cells 8l..8l+7 (lane 63 also
//    cell 512). Per step: one shfl_up pair (prev lane c7,c6), 8 cell updates
//    of 2-3 VALU each, emission loads prefetched 16 steps ahead. NO barriers,
//    NO LDS. Renormalize by wave-max every 8 steps (accumulate log2 scale).

#define L2E 1.4426950408889634f
#define LN2 0.6931471805599453f

constexpr int T = 1024;
constexpr int B = 64;
constexpr int V = 128;
constexpr int L = 256;
constexpr int R = 260;            // fp16 elems per P row: [256 labels][blank][pad]

#if __has_builtin(__builtin_amdgcn_rcpf)
#define FRCP(x) __builtin_amdgcn_rcpf(x)
#else
#define FRCP(x) (1.0f / (x))
#endif

// ---------------- prologue: emission probabilities ----------------
__global__ __launch_bounds__(256) void ctc_probs_kernel(
    const float* __restrict__ acts,        // (T, B, V)
    const int* __restrict__ labels,        // (B, L)
    ushort* __restrict__ P) {              // (B, T, R) fp16 bits
  const int w    = threadIdx.x >> 6;
  const int lane = threadIdx.x & 63;
  const int t    = blockIdx.x * 4 + w;
  const int b    = blockIdx.y;
  const float* row = acts + ((size_t)t * B + b) * V;
  float a = row[lane];
  float c = row[lane + 64];
  float mx = fmaxf(a, c);
  #pragma unroll
  for (int off = 1; off < 64; off <<= 1) mx = fmaxf(mx, __shfl_xor(mx, off));
  float mx2 = mx * L2E;
  float sm = exp2f(fmaf(a, L2E, -mx2)) + exp2f(fmaf(c, L2E, -mx2));
  #pragma unroll
  for (int off = 1; off < 64; off <<= 1) sm += __shfl_xor(sm, off);
  const float den2 = mx2 + log2f(sm);

  const int4 lv = *(const int4*)(labels + (size_t)b * L + 4 * lane);
  float p0 = exp2f(fmaf(row[lv.x], L2E, -den2));
  float p1 = exp2f(fmaf(row[lv.y], L2E, -den2));
  float p2 = exp2f(fmaf(row[lv.z], L2E, -den2));
  float p3 = exp2f(fmaf(row[lv.w], L2E, -den2));
  ushort* prow = P + ((size_t)b * T + t) * R;
  uint2 u;
  u.x = (uint)__half_as_ushort(__float2half_rn(p0)) |
        ((uint)__half_as_ushort(__float2half_rn(p1)) << 16);
  u.y = (uint)__half_as_ushort(__float2half_rn(p2)) |
        ((uint)__half_as_ushort(__float2half_rn(p3)) << 16);
  *(uint2*)(prow + 4 * lane) = u;
  if (lane == 0) {
    float pb = exp2f(fmaf(row[0], L2E, -den2));
    prow[256] = __half_as_ushort(__float2half_rn(pb));
  }
}

// ---------------- DP kernel: one wave per batch ----------------
__device__ __forceinline__ float h2f(uint bits) {
  return __half2float(__ushort_as_half((ushort)bits));
}

__global__ __launch_bounds__(64) void ctc_dp_kernel(
    const ushort* __restrict__ P,
    const int* __restrict__ labels,
    const int* __restrict__ act_lens,
    const int* __restrict__ label_lens,
    float* __restrict__ out) {
  const int b    = blockIdx.x;
  const int lane = threadIdx.x;
  const ushort* Pb = P + (size_t)b * T * R;

  // skip-transition flags for the 4 odd cells (labels 4l..4l+3)
  const int4 lv   = *(const int4*)(labels + (size_t)b * L + 4 * lane);
  const int prevw = __shfl_up(lv.w, 1);
  const float f0 = (lane > 0 && lv.x != 0 && lv.x != prevw) ? 1.f : 0.f;
  const float f1 = (lv.y != 0 && lv.y != lv.x) ? 1.f : 0.f;
  const float f2 = (lv.z != 0 && lv.z != lv.y) ? 1.f : 0.f;
  const float f3 = (lv.w != 0 && lv.w != lv.z) ? 1.f : 0.f;

  const int AL = act_lens[b];

  // ---- t=0 init (linear domain; unreachable cells = 0) ----
  float a0=0.f,a1=0.f,a2=0.f,a3=0.f,a4=0.f,a5=0.f,a6=0.f,a7=0.f,a8=0.f;
  {
    const uint2 u0 = *(const uint2*)(Pb + 4 * lane);
    const float e00 = h2f(u0.x & 0xffffu);
    const float eb0 = h2f(Pb[256]);
    if (lane == 0) { a0 = eb0; a1 = e00; }
  }
  float acc = 0.f;   // accumulated log2 of renorm scales (wave-uniform)

  auto step = [&](uint2 u, uint ub) {
    float pc7 = __shfl_up(a7, 1);
    float pc6 = __shfl_up(a6, 1);
    if (lane == 0) { pc7 = 0.f; pc6 = 0.f; }
    const float e0  = h2f(u.x & 0xffffu);
    const float e1  = h2f(u.x >> 16);
    const float e2  = h2f(u.y & 0xffffu);
    const float e3  = h2f(u.y >> 16);
    const float emb = h2f(ub);
    a8 = (a8 + a7) * emb;                    // cell 512 (valid on lane 63)
    a7 = fmaf(f3, a5, a7 + a6) * e3;
    a6 = (a6 + a5) * emb;
    a5 = fmaf(f2, a3, a5 + a4) * e2;
    a4 = (a4 + a3) * emb;
    a3 = fmaf(f1, a1, a3 + a2) * e1;
    a2 = (a2 + a1) * emb;
    a1 = fmaf(f0, pc6, a1 + a0) * e0;
    a0 = (a0 + pc7) * emb;
  };

  auto stepg = [&](uint2 u, uint ub, bool live) {
    float pc7 = __shfl_up(a7, 1);
    float pc6 = __shfl_up(a6, 1);
    if (lane == 0) { pc7 = 0.f; pc6 = 0.f; }
    const float e0  = h2f(u.x & 0xffffu);
    const float e1  = h2f(u.x >> 16);
    const float e2  = h2f(u.y & 0xffffu);
    const float e3  = h2f(u.y >> 16);
    const float emb = h2f(ub);
    const float n8 = (a8 + a7) * emb;
    const float n7 = fmaf(f3, a5, a7 + a6) * e3;
    const float n6 = (a6 + a5) * emb;
    const float n5 = fmaf(f2, a3, a5 + a4) * e2;
    const float n4 = (a4 + a3) * emb;
    const float n3 = fmaf(f1, a1, a3 + a2) * e1;
    const float n2 = (a2 + a1) * emb;
    const float n1 = fmaf(f0, pc6, a1 + a0) * e0;
    const float n0 = (a0 + pc7) * emb;
    if (live) { a8=n8; a7=n7; a6=n6; a5=n5; a4=n4; a3=n3; a2=n2; a1=n1; a0=n0; }
  };

  auto renorm = [&]() {
    float m = fmaxf(fmaxf(fmaxf(a0, a1), fmaxf(a2, a3)),
                    fmaxf(fmaxf(a4, a5), fmaxf(a6, a7)));
    if (lane == 63) m = fmaxf(m, a8);
    #pragma unroll
    for (int off = 1; off < 64; off <<= 1) m = fmaxf(m, __shfl_xor(m, off));
    m = fmaxf(m, 1e-30f);
    const float r = FRCP(m);
    acc += log2f(m);
    a0*=r; a1*=r; a2*=r; a3*=r; a4*=r; a5*=r; a6*=r; a7*=r; a8*=r;
  };

  // ---- emission prefetch pipeline: depth 16 (rows t .. t+15) ----
  uint2 ev[16];
  uint  eb[16];
  #pragma unroll
  for (int k = 0; k < 16; ++k) {
    const ushort* pr = Pb + (size_t)(1 + k) * R;
    ev[k] = *(const uint2*)(pr + 4 * lane);
    eb[k] = pr[256];
  }

  int t = 1;
  for (int blk = 0; blk < 64; ++blk) {           // 64 x 16 = steps t=1..1024
    const bool fast = (t + 16 <= AL);
    if (fast) {
      #pragma unroll
      for (int k = 0; k < 16; ++k) {
        const uint2 u = ev[k]; const uint ub = eb[k];
        int tn = t + k + 16; if (tn > T - 1) tn = T - 1;
        const ushort* pr = Pb + (size_t)tn * R;
        ev[k] = *(const uint2*)(pr + 4 * lane);
        eb[k] = pr[256];
        step(u, ub);
        if (k == 7) renorm();
      }
    } else {
      #pragma unroll
      for (int k = 0; k < 16; ++k) {
        const uint2 u = ev[k]; const uint ub = eb[k];
        int tn = t + k + 16; if (tn > T - 1) tn = T - 1;
        const ushort* pr = Pb + (size_t)tn * R;
        ev[k] = *(const uint2*)(pr + 4 * lane);
        eb[k] = pr[256];
        stepg(u, ub, (t + k) < AL);
        if (k == 7) renorm();
      }
    }
    t += 16;
    renorm();
  }

  // ---- epilogue: -ln( (a[end] + a[end-1]) * 2^acc ) ----
  const int end  = 2 * label_lens[b];
  const int base = 8 * lane;
  float sel = 0.f;
  if (base     == end || base     == end - 1) sel += a0;
  if (base + 1 == end || base + 1 == end - 1) sel += a1;
  if (base + 2 == end || base + 2 == end - 1) sel += a2;
  if (base + 3 == end || base + 3 == end - 1) sel += a3;
  if (base + 4 == end || base + 4 == end - 1) sel += a4;
  if (base + 5 == end || base + 5 == end - 1) sel += a5;
  if (base + 6 == end || base + 6 == end - 1) sel += a6;
  if (base + 7 == end || base + 7 == end - 1) sel += a7;
  if (lane == 63 && (end == 512 || end - 1 == 512)) sel += a8;
  #pragma unroll
  for (int off = 1; off < 64; off <<= 1) sel += __shfl_xor(sel, off);
  if (lane == 0) {
    const float cost = -((log2f(sel) + acc) * LN2);
    atomicAdd(out, cost);
  }
}

extern "C" void kernel_launch(void* const* d_in, const int* in_sizes, int n_in,
                              void* d_out, int out_size, void* d_ws, size_t ws_size,
                              hipStream_t stream) {
  const float* acts       = (const float*)d_in[0];
  const int*   labels     = (const int*)d_in[1];
  const int*   act_lens   = (const int*)d_in[2];
  const int*   label_lens = (const int*)d_in[3];
  float* out = (float*)d_out;
  ushort* P  = (ushort*)d_ws;   // needs B*T*R*2 = 34.1 MB

  hipMemsetAsync(out, 0, sizeof(float) * out_size, stream);
  ctc_probs_kernel<<<dim3(T / 4, B), 256, 0, stream>>>(acts, labels, P);
  ctc_dp_kernel<<<B, 64, 0, stream>>>(P, labels, act_lens, label_lens, out);
}

// Round 4
// 175.225 us; speedup vs baseline: 3.7161x; 1.2196x over previous
//
#include <hip/hip_runtime.h>
#include <hip/hip_fp16.h>
#include <math.h>

// CTC forward loss (warp-ctc semantics). T=1024, B=64, V=128, L=256, S=513.
//
// Round 4: DPP everywhere.
//  - Probs kernel: per-(t,b) softmax row -> fp16 probs at the 256 label
//    positions + blank, written to d_ws. Wave reductions via DPP
//    (row_shr/bcast + readlane), no ds_swizzle. Writes 32 zero pad rows
//    past t=T so the DP prefetch never needs clamping.
//  - DP kernel: 64 blocks x 1 wave, lane l owns cells 8l..8l+7 (+cell 512 on
//    lane 63). Cross-lane alpha via DPP wave_shr:1 (VALU pipe, lane0 -> 0).
//    Renorm every 8 steps: DPP wave-max + exponent-bits power-of-2 scale
//    (exact, no log/rcp). No barriers, no LDS, no clamps.

#define L2E 1.4426950408889634f
#define LN2 0.6931471805599453f

constexpr int T  = 1024;
constexpr int B  = 64;
constexpr int V  = 128;
constexpr int L  = 256;
constexpr int R  = 260;        // fp16 elems per P row: [256 labels][blank][pad]
constexpr int TP = T + 32;     // padded time rows per batch

// ---- DPP helpers (gfx9 ctrl codes: 0x111+ row_shr, 0x138 wave_shr:1,
//      0x142 row_bcast15, 0x143 row_bcast31) ----
template <int CTRL>
__device__ __forceinline__ float fdpp0(float x) {        // invalid lanes -> 0
  return __int_as_float(__builtin_amdgcn_update_dpp(
      0, __float_as_int(x), CTRL, 0xf, 0xf, true));
}
template <int CTRL>
__device__ __forceinline__ float fdppk(float x) {        // invalid lanes -> keep
  return __int_as_float(__builtin_amdgcn_update_dpp(
      __float_as_int(x), __float_as_int(x), CTRL, 0xf, 0xf, false));
}

__device__ __forceinline__ float wave_bcast63(float x) {
  return __int_as_float(__builtin_amdgcn_readlane(__float_as_int(x), 63));
}

__device__ __forceinline__ float wave_max(float x) {     // any sign
  x = fmaxf(x, fdppk<0x111>(x));
  x = fmaxf(x, fdppk<0x112>(x));
  x = fmaxf(x, fdppk<0x114>(x));
  x = fmaxf(x, fdppk<0x118>(x));
  x = fmaxf(x, fdppk<0x142>(x));
  x = fmaxf(x, fdppk<0x143>(x));
  return wave_bcast63(x);
}
__device__ __forceinline__ float wave_sum_nn(float x) {  // x >= 0
  x += fdpp0<0x111>(x);
  x += fdpp0<0x112>(x);
  x += fdpp0<0x114>(x);
  x += fdpp0<0x118>(x);
  x += fdpp0<0x142>(x);
  x += fdpp0<0x143>(x);
  return wave_bcast63(x);
}

// ---------------- prologue: emission probabilities ----------------
__global__ __launch_bounds__(256) void ctc_probs_kernel(
    const float* __restrict__ acts,        // (T, B, V)
    const int* __restrict__ labels,        // (B, L)
    ushort* __restrict__ P) {              // (B, TP, R) fp16 bits
  const int w    = threadIdx.x >> 6;
  const int lane = threadIdx.x & 63;
  const int t    = blockIdx.x * 4 + w;     // t in [0, TP)
  const int b    = blockIdx.y;
  ushort* prow = P + ((size_t)b * TP + t) * R;

  if (t >= T) {                            // zero pad row (520 B)
    uint2 z; z.x = 0u; z.y = 0u;
    *(uint2*)(prow + 4 * lane) = z;
    if (lane == 0) *(uint2*)(prow + 256) = z;
    return;
  }

  const float* row = acts + ((size_t)t * B + b) * V;
  const float2 v2 = *(const float2*)(row + 2 * lane);
  float mx = wave_max(fmaxf(v2.x, v2.y));
  const float mx2 = mx * L2E;
  float sm = exp2f(fmaf(v2.x, L2E, -mx2)) + exp2f(fmaf(v2.y, L2E, -mx2));
  sm = wave_sum_nn(sm);
  const float den2 = mx2 + log2f(sm);

  const int4 lv = *(const int4*)(labels + (size_t)b * L + 4 * lane);
  const float p0 = exp2f(fmaf(row[lv.x], L2E, -den2));
  const float p1 = exp2f(fmaf(row[lv.y], L2E, -den2));
  const float p2 = exp2f(fmaf(row[lv.z], L2E, -den2));
  const float p3 = exp2f(fmaf(row[lv.w], L2E, -den2));
  uint2 u;
  u.x = (uint)__half_as_ushort(__float2half_rn(p0)) |
        ((uint)__half_as_ushort(__float2half_rn(p1)) << 16);
  u.y = (uint)__half_as_ushort(__float2half_rn(p2)) |
        ((uint)__half_as_ushort(__float2half_rn(p3)) << 16);
  *(uint2*)(prow + 4 * lane) = u;
  if (lane == 0) {
    const float pb = exp2f(fmaf(row[0], L2E, -den2));
    prow[256] = __half_as_ushort(__float2half_rn(pb));
  }
}

// ---------------- DP kernel: one wave per batch ----------------
__device__ __forceinline__ float h2f(uint bits) {
  return __half2float(__ushort_as_half((ushort)bits));
}

__global__ __launch_bounds__(64) void ctc_dp_kernel(
    const ushort* __restrict__ P,
    const int* __restrict__ labels,
    const int* __restrict__ act_lens,
    const int* __restrict__ label_lens,
    float* __restrict__ out) {
  const int b    = blockIdx.x;
  const int lane = threadIdx.x;
  const ushort* __restrict__ Pb = P + (size_t)b * TP * R;

  // skip-transition flags for the 4 odd cells (labels 4l..4l+3)
  const int4 lv   = *(const int4*)(labels + (size_t)b * L + 4 * lane);
  const int prevw = __builtin_amdgcn_update_dpp(0, lv.w, 0x138, 0xf, 0xf, true);
  const float f0 = (lane > 0 && lv.x != 0 && lv.x != prevw) ? 1.f : 0.f;
  const float f1 = (lv.y != 0 && lv.y != lv.x) ? 1.f : 0.f;
  const float f2 = (lv.z != 0 && lv.z != lv.y) ? 1.f : 0.f;
  const float f3 = (lv.w != 0 && lv.w != lv.z) ? 1.f : 0.f;

  const int AL = act_lens[b];

  // ---- t=0 init (linear domain; unreachable cells = 0) ----
  float a0=0.f,a1=0.f,a2=0.f,a3=0.f,a4=0.f,a5=0.f,a6=0.f,a7=0.f,a8=0.f;
  {
    const uint2 u0 = *(const uint2*)(Pb + 4 * lane);
    const float e00 = h2f(u0.x & 0xffffu);
    const float eb0 = h2f(Pb[256]);
    if (lane == 0) { a0 = eb0; a1 = e00; }
  }
  float acc = 0.f;   // accumulated log2 of renorm scales (wave-uniform)

  auto step = [&](uint2 u, uint ub) {
    const float pc7 = fdpp0<0x138>(a7);    // prev lane's a7 (lane0 -> 0)
    const float pc6 = fdpp0<0x138>(a6);
    const float e0  = h2f(u.x & 0xffffu);
    const float e1  = h2f(u.x >> 16);
    const float e2  = h2f(u.y & 0xffffu);
    const float e3  = h2f(u.y >> 16);
    const float emb = h2f(ub);
    a8 = (a8 + a7) * emb;                  // cell 512 (valid on lane 63)
    a7 = fmaf(f3, a5, a7 + a6) * e3;
    a6 = (a6 + a5) * emb;
    a5 = fmaf(f2, a3, a5 + a4) * e2;
    a4 = (a4 + a3) * emb;
    a3 = fmaf(f1, a1, a3 + a2) * e1;
    a2 = (a2 + a1) * emb;
    a1 = fmaf(f0, pc6, a1 + a0) * e0;
    a0 = (a0 + pc7) * emb;
  };

  auto stepg = [&](uint2 u, uint ub, bool live) {
    const float pc7 = fdpp0<0x138>(a7);
    const float pc6 = fdpp0<0x138>(a6);
    const float e0  = h2f(u.x & 0xffffu);
    const float e1  = h2f(u.x >> 16);
    const float e2  = h2f(u.y & 0xffffu);
    const float e3  = h2f(u.y >> 16);
    const float emb = h2f(ub);
    const float n8 = (a8 + a7) * emb;
    const float n7 = fmaf(f3, a5, a7 + a6) * e3;
    const float n6 = (a6 + a5) * emb;
    const float n5 = fmaf(f2, a3, a5 + a4) * e2;
    const float n4 = (a4 + a3) * emb;
    const float n3 = fmaf(f1, a1, a3 + a2) * e1;
    const float n2 = (a2 + a1) * emb;
    const float n1 = fmaf(f0, pc6, a1 + a0) * e0;
    const float n0 = (a0 + pc7) * emb;
    if (live) { a8=n8; a7=n7; a6=n6; a5=n5; a4=n4; a3=n3; a2=n2; a1=n1; a0=n0; }
  };

  auto renorm = [&]() {
    float m = fmaxf(fmaxf(fmaxf(a0, a1), fmaxf(a2, a3)),
                    fmaxf(fmaxf(a4, a5), fmaxf(a6, a7)));
    m = fmaxf(m, a8);
    m = wave_max(m);                       // nonneg; keep-variant is fine
    // power-of-2 scale from exponent bits: r = 2^(127-e), exact
    int e = (int)((__float_as_uint(m) >> 23) & 0xffu);
    e = (e < 1) ? 1 : e;
    const float r = __uint_as_float((uint)(254 - e) << 23);
    acc += (float)(e - 127);
    a0*=r; a1*=r; a2*=r; a3*=r; a4*=r; a5*=r; a6*=r; a7*=r; a8*=r;
  };

  // ---- emission prefetch pipeline: depth 16 (rows t .. t+15) ----
  uint2 ev[16];
  uint  eb[16];
  #pragma unroll
  for (int k = 0; k < 16; ++k) {
    const ushort* pr = Pb + (size_t)(1 + k) * R;
    ev[k] = *(const uint2*)(pr + 4 * lane);
    eb[k] = pr[256];
  }

  const ushort* pf = Pb + (size_t)17 * R;  // row t+16 for t=1
  int t = 1;
  for (int blk = 0; blk < 64; ++blk) {     // 64 x 16 = steps t=1..1024
    const bool fast = (t + 16 <= AL);
    if (fast) {
      #pragma unroll
      for (int k = 0; k < 16; ++k) {
        const uint2 u = ev[k]; const uint ub = eb[k];
        const ushort* pr = pf + (size_t)k * R;       // row t+k+16 (pad-safe)
        ev[k] = *(const uint2*)(pr + 4 * lane);
        eb[k] = pr[256];
        step(u, ub);
        if (k == 7) renorm();
      }
    } else {
      #pragma unroll
      for (int k = 0; k < 16; ++k) {
        const uint2 u = ev[k]; const uint ub = eb[k];
        const ushort* pr = pf + (size_t)k * R;
        ev[k] = *(const uint2*)(pr + 4 * lane);
        eb[k] = pr[256];
        stepg(u, ub, (t + k) < AL);
        if (k == 7) renorm();
      }
    }
    t += 16;
    pf += (size_t)16 * R;
    renorm();
  }

  // ---- epilogue: -ln( (a[end] + a[end-1]) * 2^acc ) ----
  const int end  = 2 * label_lens[b];
  const int base = 8 * lane;
  float sel = 0.f;
  if (base     == end || base     == end - 1) sel += a0;
  if (base + 1 == end || base + 1 == end - 1) sel += a1;
  if (base + 2 == end || base + 2 == end - 1) sel += a2;
  if (base + 3 == end || base + 3 == end - 1) sel += a3;
  if (base + 4 == end || base + 4 == end - 1) sel += a4;
  if (base + 5 == end || base + 5 == end - 1) sel += a5;
  if (base + 6 == end || base + 6 == end - 1) sel += a6;
  if (base + 7 == end || base + 7 == end - 1) sel += a7;
  if (lane == 63 && (end == 512 || end - 1 == 512)) sel += a8;
  sel = wave_sum_nn(sel);
  if (lane == 0) {
    const float cost = -((log2f(sel) + acc) * LN2);
    atomicAdd(out, cost);
  }
}

extern "C" void kernel_launch(void* const* d_in, const int* in_sizes, int n_in,
                              void* d_out, int out_size, void* d_ws, size_t ws_size,
                              hipStream_t stream) {
  const float* acts       = (const float*)d_in[0];
  const int*   labels     = (const int*)d_in[1];
  const int*   act_lens   = (const int*)d_in[2];
  const int*   label_lens = (const int*)d_in[3];
  float* out = (float*)d_out;
  ushort* P  = (ushort*)d_ws;   // needs B*TP*R*2 = 35.1 MB

  hipMemsetAsync(out, 0, sizeof(float) * out_size, stream);
  ctc_probs_kernel<<<dim3(TP / 4, B), 256, 0, stream>>>(acts, labels, P);
  ctc_dp_kernel<<<B, 64, 0, stream>>>(P, labels, act_lens, label_lens, out);
}